// Round 1
// 182.235 us; speedup vs baseline: 1.1524x; 1.1524x over previous
//
#include <hip/hip_runtime.h>
#include <stdint.h>

#define H 256
#define EPS 1e-8f

typedef __bf16 bf16x8 __attribute__((ext_vector_type(8)));
typedef float  f32x4  __attribute__((ext_vector_type(4)));

__device__ __forceinline__ unsigned short f2bf(float f) {
  unsigned u = __builtin_bit_cast(unsigned, f);
  u += 0x7FFFu + ((u >> 16) & 1u);            // round-to-nearest-even
  return (unsigned short)(u >> 16);
}
__device__ __forceinline__ float bflo(unsigned u){ return __builtin_bit_cast(float, u << 16); }
__device__ __forceinline__ float bfhi(unsigned u){ return __builtin_bit_cast(float, u & 0xFFFF0000u); }

__device__ __forceinline__ void g2l16(const void* g, void* l) {
  __builtin_amdgcn_global_load_lds((__attribute__((address_space(1))) void*)g,
                                   (__attribute__((address_space(3))) void*)l, 16, 0, 0);
}

// fp32 -> bf16 bits, zero-fill beyond `valid` (row padding for GEMM tiles)
__global__ __launch_bounds__(256) void conv_bf16_kernel(
    const float* __restrict__ src, unsigned short* __restrict__ dst, int valid, int total) {
  int i = (blockIdx.x * 256 + threadIdx.x) * 4;
  if (i >= total) return;
  float4 v = make_float4(0.f, 0.f, 0.f, 0.f);
  if (i < valid) v = *(const float4*)(src + i);
  ushort4 o;
  o.x = f2bf(v.x); o.y = f2bf(v.y); o.z = f2bf(v.z); o.w = f2bf(v.w);
  *(ushort4*)(dst + i) = o;
}

// C[Mp,256] = act(A[Mp,256] @ B[256,256]^T + bias), bf16 in/out, fp32 accum.
// m97-style: 128x128 block tile, 4 waves in 2x2, each wave 4x4 MFMA subtiles,
// BK=32, global_load_lds width-16 staging, single-buffered LDS.
template<bool RELU>
__global__ __launch_bounds__(256) void gemm_bt_kernel(
    const unsigned short* __restrict__ A,
    const unsigned short* __restrict__ B,
    const float* __restrict__ bias,
    unsigned short* __restrict__ C) {
  __shared__ unsigned short sA[128 * 32];
  __shared__ unsigned short sB[128 * 32];
  const int tid  = threadIdx.x;
  const int wave = tid >> 6, lane = tid & 63;
  const int quad = lane >> 4, l16 = lane & 15;
  const int wm = wave & 1, wn = wave >> 1;
  const size_t bm = blockIdx.x, bn = blockIdx.y;

  // staging: per wave 2 calls per tile; call c covers rows (wave*2+c)*16 .. +16
  const int srow0 = (wave * 2 + 0) * 16 + (lane >> 2);
  const int srow1 = (wave * 2 + 1) * 16 + (lane >> 2);
  const int kch   = (lane & 3) * 8;                      // 8 bf16 = 16 B chunk
  const unsigned short* gA0 = A + ((bm * 128 + srow0) * H + kch);
  const unsigned short* gA1 = A + ((bm * 128 + srow1) * H + kch);
  const unsigned short* gB0 = B + ((bn * 128 + srow0) * H + kch);
  const unsigned short* gB1 = B + ((bn * 128 + srow1) * H + kch);
  unsigned short* lA0 = sA + (wave * 2 + 0) * 512 + lane * 8;
  unsigned short* lA1 = sA + (wave * 2 + 1) * 512 + lane * 8;
  unsigned short* lB0 = sB + (wave * 2 + 0) * 512 + lane * 8;
  unsigned short* lB1 = sB + (wave * 2 + 1) * 512 + lane * 8;

  f32x4 acc[4][4];
#pragma unroll
  for (int i = 0; i < 4; i++)
#pragma unroll
    for (int j = 0; j < 4; j++) acc[i][j] = (f32x4){0.f, 0.f, 0.f, 0.f};

#pragma unroll
  for (int kk = 0; kk < H / 32; ++kk) {
    const int k0 = kk * 32;
    if (kk) __syncthreads();                 // prior ds_reads done before overwrite
    g2l16(gA0 + k0, lA0);
    g2l16(gA1 + k0, lA1);
    g2l16(gB0 + k0, lB0);
    g2l16(gB1 + k0, lB1);
    __syncthreads();                         // vmcnt(0) drain: LDS tiles visible

    bf16x8 af[4], bfr[4];
#pragma unroll
    for (int i = 0; i < 4; i++)
      af[i] = *(const bf16x8*)(sA + ((wm * 64 + i * 16 + l16) * 32 + quad * 8));
#pragma unroll
    for (int j = 0; j < 4; j++)
      bfr[j] = *(const bf16x8*)(sB + ((wn * 64 + j * 16 + l16) * 32 + quad * 8));
#pragma unroll
    for (int i = 0; i < 4; i++)
#pragma unroll
      for (int j = 0; j < 4; j++)
        acc[i][j] = __builtin_amdgcn_mfma_f32_16x16x32_bf16(af[i], bfr[j], acc[i][j], 0, 0, 0);
  }

  // epilogue: C/D layout col=lane&15, row=quad*4+reg (m89/m91-verified)
  const int row_base = (int)bm * 128 + wm * 64;
  const int col_base = (int)bn * 128 + wn * 64;
#pragma unroll
  for (int j = 0; j < 4; j++) {
    const int col = col_base + j * 16 + l16;
    const float bv = bias[col];
#pragma unroll
    for (int i = 0; i < 4; i++) {
#pragma unroll
      for (int r = 0; r < 4; r++) {
        const int row = row_base + i * 16 + quad * 4 + r;
        float v = acc[i][j][r] + bv;
        if (RELU) v = fmaxf(v, 0.f);
        C[(size_t)row * H + col] = f2bf(v);
      }
    }
  }
}

// per-node reciprocal norm: rn[i] = 1/max(||g_i||, eps), one wave per row
__global__ __launch_bounds__(256) void rownorm_kernel(
    const unsigned short* __restrict__ g, float* __restrict__ rn, int n) {
  int row = blockIdx.x * 4 + (threadIdx.x >> 6);
  if (row >= n) return;
  int lane = threadIdx.x & 63;
  uint2 a = ((const uint2*)(g + (size_t)row * H))[lane];
  float x0 = bflo(a.x), x1 = bfhi(a.x), x2 = bflo(a.y), x3 = bfhi(a.y);
  float ss = x0 * x0 + x1 * x1 + x2 * x2 + x3 * x3;
#pragma unroll
  for (int off = 32; off; off >>= 1) ss += __shfl_down(ss, off, 64);
  if (lane == 0) rn[row] = 1.f / fmaxf(sqrtf(ss), EPS);
}

__device__ __forceinline__ float dot_u4(uint4 a, uint4 b) {
  float s;
  s  = bflo(a.x) * bflo(b.x) + bfhi(a.x) * bfhi(b.x);
  s += bflo(a.y) * bflo(b.y) + bfhi(a.y) * bfhi(b.y);
  s += bflo(a.z) * bflo(b.z) + bfhi(a.z) * bfhi(b.z);
  s += bflo(a.w) * bflo(b.w) + bfhi(a.w) * bfhi(b.w);
  return s;
}

// 8 lanes per edge, 8 edges per wave, 32 edges per block.
// Each lane: 8 independent dwordx4 gathers (4 chunks x 2 rows), 3-step
// width-8 shfl_xor reduce. Latency-bound kernel -> maximize loads in flight,
// minimize dependent shuffle chain, amortize per-wave overhead 8x.
__global__ __launch_bounds__(256) void edge_cos_kernel(
    const int* __restrict__ ei, const unsigned short* __restrict__ g,
    const float* __restrict__ rn, float* __restrict__ out, int E) {
  const int lane = threadIdx.x & 63;
  const int wid  = threadIdx.x >> 6;
  const int l8   = lane & 7;           // position within the edge's 8-lane group
  const int sub  = lane >> 3;          // which of the wave's 8 edges
  const int e    = blockIdx.x * 32 + wid * 8 + sub;
  if (e >= E) return;
  const int c = ei[e], r = ei[E + e];
  const uint4* gc = (const uint4*)(g + (size_t)c * H);  // row = 32 uint4
  const uint4* gr = (const uint4*)(g + (size_t)r * H);
  // issue all 8 gathers before any use
  uint4 a0 = gc[l8], a1 = gc[l8 + 8], a2 = gc[l8 + 16], a3 = gc[l8 + 24];
  uint4 b0 = gr[l8], b1 = gr[l8 + 8], b2 = gr[l8 + 16], b3 = gr[l8 + 24];
  float d = dot_u4(a0, b0) + dot_u4(a1, b1) + dot_u4(a2, b2) + dot_u4(a3, b3);
  d += __shfl_xor(d, 4, 8);
  d += __shfl_xor(d, 2, 8);
  d += __shfl_xor(d, 1, 8);
  if (l8 == 0) out[e] = d * rn[c] * rn[r];
}

extern "C" void kernel_launch(void* const* d_in, const int* in_sizes, int n_in,
                              void* d_out, int out_size, void* d_ws, size_t ws_size,
                              hipStream_t stream) {
  const float* emb = (const float*)d_in[0];
  const int*   ei  = (const int*)d_in[1];
  const float* W1  = (const float*)d_in[2];
  const float* b1  = (const float*)d_in[3];
  const float* W2  = (const float*)d_in[4];
  const float* b2  = (const float*)d_in[5];
  float* out = (float*)d_out;

  const int NH = in_sizes[0];              // N*H
  const int N  = NH / H;                   // 50000
  const int E  = in_sizes[1] / 2;          // 300000
  const int Mp = ((N + 127) / 128) * 128;  // 50048

  char* ws = (char*)d_ws;
  unsigned short* embB = (unsigned short*)ws; ws += (size_t)Mp * H * 2;
  unsigned short* hB   = (unsigned short*)ws; ws += (size_t)Mp * H * 2;
  unsigned short* gB   = (unsigned short*)ws; ws += (size_t)Mp * H * 2;
  unsigned short* w1B  = (unsigned short*)ws; ws += (size_t)H * H * 2;
  unsigned short* w2B  = (unsigned short*)ws; ws += (size_t)H * H * 2;
  float* rn            = (float*)ws;

  conv_bf16_kernel<<<(Mp * H / 4 + 255) / 256, 256, 0, stream>>>(emb, embB, NH, Mp * H);
  conv_bf16_kernel<<<(H * H / 4 + 255) / 256, 256, 0, stream>>>(W1, w1B, H * H, H * H);
  conv_bf16_kernel<<<(H * H / 4 + 255) / 256, 256, 0, stream>>>(W2, w2B, H * H, H * H);

  dim3 ggrid(Mp / 128, H / 128);
  gemm_bt_kernel<true ><<<ggrid, 256, 0, stream>>>(embB, w1B, b1, hB);
  gemm_bt_kernel<false><<<ggrid, 256, 0, stream>>>(hB, w2B, b2, gB);

  rownorm_kernel<<<(N + 3) / 4, 256, 0, stream>>>(gB, rn, N);
  edge_cos_kernel<<<(E + 31) / 32, 256, 0, stream>>>(ei, gB, rn, out, E);
}

// Round 4
// 165.692 us; speedup vs baseline: 1.2674x; 1.0998x over previous
//
#include <hip/hip_runtime.h>
#include <stdint.h>

#define H 256
#define EPS 1e-8f

typedef __bf16 bf16x8 __attribute__((ext_vector_type(8)));
typedef float  f32x4  __attribute__((ext_vector_type(4)));

__device__ __forceinline__ unsigned short f2bf(float f) {
  unsigned u = __builtin_bit_cast(unsigned, f);
  u += 0x7FFFu + ((u >> 16) & 1u);            // round-to-nearest-even
  return (unsigned short)(u >> 16);
}
__device__ __forceinline__ float bflo(unsigned u){ return __builtin_bit_cast(float, u << 16); }
__device__ __forceinline__ float bfhi(unsigned u){ return __builtin_bit_cast(float, u & 0xFFFF0000u); }

__device__ __forceinline__ void g2l16(const void* g, void* l) {
  __builtin_amdgcn_global_load_lds((__attribute__((address_space(1))) void*)g,
                                   (__attribute__((address_space(3))) void*)l, 16, 0, 0);
}

// fp32 -> bf16 bits, zero-fill beyond `valid` (row padding for GEMM tiles)
__global__ __launch_bounds__(256) void conv_bf16_kernel(
    const float* __restrict__ src, unsigned short* __restrict__ dst, int valid, int total) {
  int i = (blockIdx.x * 256 + threadIdx.x) * 4;
  if (i >= total) return;
  float4 v = make_float4(0.f, 0.f, 0.f, 0.f);
  if (i < valid) v = *(const float4*)(src + i);
  ushort4 o;
  o.x = f2bf(v.x); o.y = f2bf(v.y); o.z = f2bf(v.z); o.w = f2bf(v.w);
  *(ushort4*)(dst + i) = o;
}

// both 256x256 weight matrices in one launch (grid = 2*H*H/4/256 = 128)
__global__ __launch_bounds__(256) void conv_w_kernel(
    const float* __restrict__ W1, const float* __restrict__ W2,
    unsigned short* __restrict__ w1B, unsigned short* __restrict__ w2B) {
  int i = (blockIdx.x * 256 + threadIdx.x) * 4;
  const int HH = H * H;
  if (i >= 2 * HH) return;
  const float* s = (i < HH) ? W1 : W2;
  unsigned short* d = (i < HH) ? w1B : w2B;
  int j = (i < HH) ? i : i - HH;
  float4 v = *(const float4*)(s + j);
  ushort4 o;
  o.x = f2bf(v.x); o.y = f2bf(v.y); o.z = f2bf(v.z); o.w = f2bf(v.w);
  *(ushort4*)(d + j) = o;
}

// Fused MLP: g = relu(emb@W1^T + b1)@W2^T + b2, plus rn[i] = 1/max(||g_i||,eps).
// Block = 64 emb-rows x full 256 cols, 4 waves (wr: 32-row half, wn: 128-col half).
// GEMM1 SWAPPED: acc = mfma(A=W1frag, B=embfrag) -> D holds h^T:
//   lane l16 = h-row, reg (quad*4+r) = h-col. So the h epilogue packs 4
//   consecutive h-cols per lane into one ds_write_b64 (row-major sH), and
//   GEMM2's A-frag (lane = row, 8 contiguous k) is a plain ds_read_b128.
// sH XOR-swizzle byte^=((row&7)<<4): 16B-granule, write 2-way (free), read ok.
// W2 tile 0 prefetched via global_load_lds under the h epilogue (T14).
__global__ __launch_bounds__(256) void fused_mlp_kernel(
    const unsigned short* __restrict__ A,   // embB [Mp][H] bf16 (zero-padded)
    const unsigned short* __restrict__ W1,  // [H][H] bf16, row = out-col
    const unsigned short* __restrict__ W2,
    const float* __restrict__ b1, const float* __restrict__ b2,
    unsigned short* __restrict__ G,         // gB out [Mp][H] bf16
    float* __restrict__ rn) {
  __shared__ unsigned short sA[64 * 32];     // 4 KB  emb tile
  __shared__ unsigned short sW[256 * 32];    // 16 KB W1 tile
  __shared__ unsigned short sW2[256 * 32];   // 16 KB W2 tile
  __shared__ unsigned short sH[64 * 256];    // 32 KB h (swizzled)
  __shared__ float ssb[64][2];               // rownorm partials per col-half

  const int tid  = threadIdx.x;
  const int wave = tid >> 6, lane = tid & 63;
  const int quad = lane >> 4, l16 = lane & 15;
  const int wr = wave >> 1, wn = wave & 1;
  const size_t bm = blockIdx.x;

  // staging: sA one g2l16/thread, sW/sW2 four (call c covers 64 rows)
  const int arow = tid >> 2, kch = (tid & 3) * 8;
  const unsigned short* gA  = A  + ((bm * 64 + arow) * H + kch);
  const unsigned short* gW1 = W1 + (size_t)arow * H + kch;
  const unsigned short* gW2 = W2 + (size_t)arow * H + kch;
  unsigned short* lA  = sA  + tid * 8;
  unsigned short* lW  = sW  + tid * 8;
  unsigned short* lW2 = sW2 + tid * 8;

  // ---------------- GEMM1 (swapped): acc[iC][jR] = h^T subtiles -------------
  f32x4 acc[8][2];
#pragma unroll
  for (int i = 0; i < 8; i++)
#pragma unroll
    for (int j = 0; j < 2; j++) acc[i][j] = (f32x4){0.f, 0.f, 0.f, 0.f};

#pragma unroll
  for (int ks = 0; ks < 8; ++ks) {
    const int k0 = ks * 32;
    if (ks) __syncthreads();
    g2l16(gA + k0, lA);
#pragma unroll
    for (int c = 0; c < 4; c++)
      g2l16(gW1 + (size_t)(c * 64) * H + k0, lW + c * 2048);
    __syncthreads();

    bf16x8 wf[8], af[2];
#pragma unroll
    for (int i = 0; i < 8; i++)
      wf[i] = *(const bf16x8*)(sW + ((wn * 128 + i * 16 + l16) * 32 + quad * 8));
#pragma unroll
    for (int j = 0; j < 2; j++)
      af[j] = *(const bf16x8*)(sA + ((wr * 32 + j * 16 + l16) * 32 + quad * 8));
#pragma unroll
    for (int i = 0; i < 8; i++)
#pragma unroll
      for (int j = 0; j < 2; j++)
        acc[i][j] = __builtin_amdgcn_mfma_f32_16x16x32_bf16(wf[i], af[j], acc[i][j], 0, 0, 0);
  }

  // prefetch W2 k-tile 0 while the h epilogue runs
#pragma unroll
  for (int c = 0; c < 4; c++)
    g2l16(gW2 + (size_t)(c * 64) * H, lW2 + c * 2048);

  // ------------- h epilogue: +b1, relu, bf16, packed b64 into sH ------------
#pragma unroll
  for (int i = 0; i < 8; i++) {
    const int hcol = wn * 128 + i * 16 + quad * 4;
    const float4 bv = *(const float4*)(b1 + hcol);
#pragma unroll
    for (int j = 0; j < 2; j++) {
      const int row = wr * 32 + j * 16 + l16;
      f32x4 v = acc[i][j];
      unsigned short h0 = f2bf(fmaxf(v[0] + bv.x, 0.f));
      unsigned short h1 = f2bf(fmaxf(v[1] + bv.y, 0.f));
      unsigned short h2 = f2bf(fmaxf(v[2] + bv.z, 0.f));
      unsigned short h3 = f2bf(fmaxf(v[3] + bv.w, 0.f));
      uint2 p;
      p.x = (unsigned)h0 | ((unsigned)h1 << 16);
      p.y = (unsigned)h2 | ((unsigned)h3 << 16);
      unsigned off = (unsigned)(row * 512 + hcol * 2) ^ ((unsigned)(row & 7) << 4);
      *(uint2*)((char*)sH + off) = p;
    }
  }

  __syncthreads();   // sH visible to wn-pair; W2 tile 0 drained

  // ---------------- GEMM2 (normal): acc2[iR][j] = g subtiles ----------------
  f32x4 acc2[2][8];
#pragma unroll
  for (int i = 0; i < 2; i++)
#pragma unroll
    for (int j = 0; j < 8; j++) acc2[i][j] = (f32x4){0.f, 0.f, 0.f, 0.f};

#pragma unroll
  for (int ks = 0; ks < 8; ++ks) {
    if (ks) {
      __syncthreads();
#pragma unroll
      for (int c = 0; c < 4; c++)
        g2l16(gW2 + (size_t)(c * 64) * H + ks * 32, lW2 + c * 2048);
      __syncthreads();
    }
    bf16x8 hf[2], wf2[8];
#pragma unroll
    for (int i = 0; i < 2; i++) {
      const int hrow = wr * 32 + i * 16 + l16;
      unsigned off = (unsigned)(hrow * 512 + ks * 64 + quad * 16) ^ ((unsigned)(hrow & 7) << 4);
      hf[i] = *(const bf16x8*)((const char*)sH + off);
    }
#pragma unroll
    for (int j = 0; j < 8; j++)
      wf2[j] = *(const bf16x8*)(sW2 + ((wn * 128 + j * 16 + l16) * 32 + quad * 8));
#pragma unroll
    for (int i = 0; i < 2; i++)
#pragma unroll
      for (int j = 0; j < 8; j++)
        acc2[i][j] = __builtin_amdgcn_mfma_f32_16x16x32_bf16(hf[i], wf2[j], acc2[i][j], 0, 0, 0);
  }

  // --------- final epilogue: +b2, rownorm (in-block), bf16 g writes ---------
  float b2v[8];
#pragma unroll
  for (int j = 0; j < 8; j++) b2v[j] = b2[wn * 128 + j * 16 + l16];
#pragma unroll
  for (int i = 0; i < 2; i++)
#pragma unroll
    for (int j = 0; j < 8; j++)
#pragma unroll
      for (int r = 0; r < 4; r++) acc2[i][j][r] += b2v[j];

  float ss[2][4];
#pragma unroll
  for (int i = 0; i < 2; i++)
#pragma unroll
    for (int r = 0; r < 4; r++) {
      float s = 0.f;
#pragma unroll
      for (int j = 0; j < 8; j++) s += acc2[i][j][r] * acc2[i][j][r];
      ss[i][r] = s;
    }
#pragma unroll
  for (int m = 1; m < 16; m <<= 1)
#pragma unroll
    for (int i = 0; i < 2; i++)
#pragma unroll
      for (int r = 0; r < 4; r++) ss[i][r] += __shfl_xor(ss[i][r], m, 64);
  if (l16 == 0) {
#pragma unroll
    for (int i = 0; i < 2; i++)
#pragma unroll
      for (int r = 0; r < 4; r++) ssb[wr * 32 + i * 16 + quad * 4 + r][wn] = ss[i][r];
  }
  __syncthreads();
  if (tid < 64) {
    float s2 = ssb[tid][0] + ssb[tid][1];
    rn[bm * 64 + tid] = 1.f / fmaxf(sqrtf(s2), EPS);
  }

#pragma unroll
  for (int i = 0; i < 2; i++)
#pragma unroll
    for (int j = 0; j < 8; j++) {
      const int gcol = wn * 128 + j * 16 + l16;
#pragma unroll
      for (int r = 0; r < 4; r++) {
        const size_t grow = bm * 64 + wr * 32 + i * 16 + quad * 4 + r;
        G[grow * H + gcol] = f2bf(acc2[i][j][r]);
      }
    }
}

__device__ __forceinline__ float dot_u4(uint4 a, uint4 b) {
  float s;
  s  = bflo(a.x) * bflo(b.x) + bfhi(a.x) * bfhi(b.x);
  s += bflo(a.y) * bflo(b.y) + bfhi(a.y) * bfhi(b.y);
  s += bflo(a.z) * bflo(b.z) + bfhi(a.z) * bfhi(b.z);
  s += bflo(a.w) * bflo(b.w) + bfhi(a.w) * bfhi(b.w);
  return s;
}

// 8 lanes per edge, 8 edges per wave, 32 edges per block.
__global__ __launch_bounds__(256) void edge_cos_kernel(
    const int* __restrict__ ei, const unsigned short* __restrict__ g,
    const float* __restrict__ rn, float* __restrict__ out, int E) {
  const int lane = threadIdx.x & 63;
  const int wid  = threadIdx.x >> 6;
  const int l8   = lane & 7;
  const int sub  = lane >> 3;
  const int e    = blockIdx.x * 32 + wid * 8 + sub;
  if (e >= E) return;
  const int c = ei[e], r = ei[E + e];
  const uint4* gc = (const uint4*)(g + (size_t)c * H);
  const uint4* gr = (const uint4*)(g + (size_t)r * H);
  uint4 a0 = gc[l8], a1 = gc[l8 + 8], a2 = gc[l8 + 16], a3 = gc[l8 + 24];
  uint4 b0 = gr[l8], b1 = gr[l8 + 8], b2 = gr[l8 + 16], b3 = gr[l8 + 24];
  float d = dot_u4(a0, b0) + dot_u4(a1, b1) + dot_u4(a2, b2) + dot_u4(a3, b3);
  d += __shfl_xor(d, 4, 8);
  d += __shfl_xor(d, 2, 8);
  d += __shfl_xor(d, 1, 8);
  if (l8 == 0) out[e] = d * rn[c] * rn[r];
}

extern "C" void kernel_launch(void* const* d_in, const int* in_sizes, int n_in,
                              void* d_out, int out_size, void* d_ws, size_t ws_size,
                              hipStream_t stream) {
  const float* emb = (const float*)d_in[0];
  const int*   ei  = (const int*)d_in[1];
  const float* W1  = (const float*)d_in[2];
  const float* b1  = (const float*)d_in[3];
  const float* W2  = (const float*)d_in[4];
  const float* b2  = (const float*)d_in[5];
  float* out = (float*)d_out;

  const int NH = in_sizes[0];              // N*H
  const int N  = NH / H;                   // 50000
  const int E  = in_sizes[1] / 2;          // 300000
  const int Mp = ((N + 63) / 64) * 64;     // 50048 (multiple of 64)

  char* ws = (char*)d_ws;
  unsigned short* embB = (unsigned short*)ws; ws += (size_t)Mp * H * 2;
  unsigned short* gB   = (unsigned short*)ws; ws += (size_t)Mp * H * 2;
  unsigned short* w1B  = (unsigned short*)ws; ws += (size_t)H * H * 2;
  unsigned short* w2B  = (unsigned short*)ws; ws += (size_t)H * H * 2;
  float* rn            = (float*)ws;

  conv_bf16_kernel<<<(Mp * H / 4 + 255) / 256, 256, 0, stream>>>(emb, embB, NH, Mp * H);
  conv_w_kernel<<<(2 * H * H / 4 + 255) / 256, 256, 0, stream>>>(W1, W2, w1B, w2B);

  fused_mlp_kernel<<<Mp / 64, 256, 0, stream>>>(embB, w1B, w2B, b1, b2, gB, rn);

  edge_cos_kernel<<<(E + 31) / 32, 256, 0, stream>>>(ei, gB, rn, out, E);
}

// Round 5
// 155.299 us; speedup vs baseline: 1.3522x; 1.0669x over previous
//
#include <hip/hip_runtime.h>
#include <stdint.h>

#define H 256
#define EPS 1e-8f

typedef __bf16 bf16x8 __attribute__((ext_vector_type(8)));
typedef float  f32x4  __attribute__((ext_vector_type(4)));

__device__ __forceinline__ unsigned short f2bf(float f) {
  unsigned u = __builtin_bit_cast(unsigned, f);
  u += 0x7FFFu + ((u >> 16) & 1u);            // round-to-nearest-even
  return (unsigned short)(u >> 16);
}
__device__ __forceinline__ float bflo(unsigned u){ return __builtin_bit_cast(float, u << 16); }
__device__ __forceinline__ float bfhi(unsigned u){ return __builtin_bit_cast(float, u & 0xFFFF0000u); }

__device__ __forceinline__ void g2l16(const void* g, void* l) {
  __builtin_amdgcn_global_load_lds((__attribute__((address_space(1))) void*)g,
                                   (__attribute__((address_space(3))) void*)l, 16, 0, 0);
}

// both 256x256 weight matrices in one launch (grid = 2*H*H/4/256 = 128)
__global__ __launch_bounds__(256) void conv_w_kernel(
    const float* __restrict__ W1, const float* __restrict__ W2,
    unsigned short* __restrict__ w1B, unsigned short* __restrict__ w2B) {
  int i = (blockIdx.x * 256 + threadIdx.x) * 4;
  const int HH = H * H;
  if (i >= 2 * HH) return;
  const float* s = (i < HH) ? W1 : W2;
  unsigned short* d = (i < HH) ? w1B : w2B;
  int j = (i < HH) ? i : i - HH;
  float4 v = *(const float4*)(s + j);
  ushort4 o;
  o.x = f2bf(v.x); o.y = f2bf(v.y); o.z = f2bf(v.z); o.w = f2bf(v.w);
  *(ushort4*)(d + j) = o;
}

// Fused MLP: g = relu(emb@W1^T + b1)@W2^T + b2, plus rn[i] = 1/max(||g_i||,eps).
// Round-5 schedule rework (math identical to round-4, which passed):
//  - A read DIRECTLY from fp32 emb (conv_emb kernel eliminated): global float4
//    loads issued 3 k-steps (~600cyc) ahead into a statically-indexed 3-slot
//    VGPR ring, converted with the same f2bf, ds_write_b128 into sA.
//  - Double-buffered sA[2] (8KB) and weight tile sW[2] (32KB, shared W1->W2).
//    One barrier per k-step; stage of tile k+1 issued before compute of k.
//  - W2 tile 0 prefetched into the freed sW half during GEMM1's last k-step.
// LDS 8+32+32+0.5 = 72.5 KB -> 2 blocks/CU (unchanged).
__global__ __launch_bounds__(256) void fused_mlp_kernel(
    const float* __restrict__ Af,           // emb fp32 [N][H]
    const unsigned short* __restrict__ W1,  // [H][H] bf16, row = out-col
    const unsigned short* __restrict__ W2,
    const float* __restrict__ b1, const float* __restrict__ b2,
    unsigned short* __restrict__ G,         // gB out [Mp][H] bf16
    float* __restrict__ rn, int N) {
  __shared__ unsigned short sA[2][64 * 32];   // 8 KB  emb tile (dbuf)
  __shared__ unsigned short sW[2][256 * 32];  // 32 KB weight tile (dbuf, W1 then W2)
  __shared__ unsigned short sH[64 * 256];     // 32 KB h (swizzled)
  __shared__ float ssb[64][2];                // rownorm partials per col-half

  const int tid  = threadIdx.x;
  const int wave = tid >> 6, lane = tid & 63;
  const int quad = lane >> 4, l16 = lane & 15;
  const int wr = wave >> 1, wn = wave & 1;
  const size_t bm = blockIdx.x;

  // staging geometry: thread -> (row, 8-elem k-chunk); sA/sW are row-major [r][32]
  const int arow = tid >> 2, kch = (tid & 3) * 8;
  const int grow = (int)bm * 64 + arow;
  const bool avalid = grow < N;
  const float* gAf = Af + (size_t)grow * H + kch;
  const unsigned short* gW1 = W1 + (size_t)arow * H + kch;
  const unsigned short* gW2 = W2 + (size_t)arow * H + kch;

  float4 ra[3][2];
#define LOAD_A(kt, slot)                                                        \
  do {                                                                          \
    if (avalid) {                                                               \
      ra[slot][0] = *(const float4*)(gAf + (kt) * 32);                          \
      ra[slot][1] = *(const float4*)(gAf + (kt) * 32 + 4);                      \
    } else {                                                                    \
      ra[slot][0] = make_float4(0.f, 0.f, 0.f, 0.f);                            \
      ra[slot][1] = make_float4(0.f, 0.f, 0.f, 0.f);                            \
    }                                                                           \
  } while (0)
#define WRITE_A(buf, slot)                                                      \
  do {                                                                          \
    uint4 p;                                                                    \
    p.x = (unsigned)f2bf(ra[slot][0].x) | ((unsigned)f2bf(ra[slot][0].y) << 16);\
    p.y = (unsigned)f2bf(ra[slot][0].z) | ((unsigned)f2bf(ra[slot][0].w) << 16);\
    p.z = (unsigned)f2bf(ra[slot][1].x) | ((unsigned)f2bf(ra[slot][1].y) << 16);\
    p.w = (unsigned)f2bf(ra[slot][1].z) | ((unsigned)f2bf(ra[slot][1].w) << 16);\
    *(uint4*)(&sA[buf][tid * 8]) = p;                                           \
  } while (0)
#define STAGE_W(gW, kt, buf)                                                    \
  do {                                                                          \
    _Pragma("unroll")                                                           \
    for (int c = 0; c < 4; c++)                                                 \
      g2l16((gW) + (size_t)(c * 64) * H + (kt) * 32, &sW[buf][c * 2048 + tid * 8]); \
  } while (0)

  // ---------------- GEMM1 (swapped): acc[iC][jR] = h^T subtiles -------------
  f32x4 acc[8][2];
#pragma unroll
  for (int i = 0; i < 8; i++)
#pragma unroll
    for (int j = 0; j < 2; j++) acc[i][j] = (f32x4){0.f, 0.f, 0.f, 0.f};

  // prologue: A for kt=0..2 in flight, A0 + W1_0 staged
  LOAD_A(0, 0); LOAD_A(1, 1); LOAD_A(2, 2);
  WRITE_A(0, 0);
  STAGE_W(gW1, 0, 0);
  __syncthreads();

#pragma unroll
  for (int kt = 0; kt < 8; ++kt) {
    if (kt < 5) LOAD_A(kt + 3, (kt + 3) % 3);            // 3-ahead HBM prefetch
    if (kt < 7) STAGE_W(gW1, kt + 1, (kt + 1) & 1);      // 1-ahead L2 prefetch
    if (kt == 7) STAGE_W(gW2, 0, 0);                     // W2_0 into freed half

    bf16x8 wf[8], af[2];
#pragma unroll
    for (int i = 0; i < 8; i++)
      wf[i] = *(const bf16x8*)(&sW[kt & 1][(wn * 128 + i * 16 + l16) * 32 + quad * 8]);
#pragma unroll
    for (int j = 0; j < 2; j++)
      af[j] = *(const bf16x8*)(&sA[kt & 1][(wr * 32 + j * 16 + l16) * 32 + quad * 8]);

    if (kt < 7) WRITE_A((kt + 1) & 1, (kt + 1) % 3);     // cvt + ds_write next A

#pragma unroll
    for (int i = 0; i < 8; i++)
#pragma unroll
      for (int j = 0; j < 2; j++)
        acc[i][j] = __builtin_amdgcn_mfma_f32_16x16x32_bf16(wf[i], af[j], acc[i][j], 0, 0, 0);
    __syncthreads();   // single barrier per k-step: stages drained, reads done
  }

  // ------------- h epilogue: +b1, relu, bf16, packed b64 into sH ------------
  // layout (m89/m91-verified, round-4-passed): lane l16 = h-row, reg = h-col
#pragma unroll
  for (int i = 0; i < 8; i++) {
    const int hcol = wn * 128 + i * 16 + quad * 4;
    const float4 bv = *(const float4*)(b1 + hcol);
#pragma unroll
    for (int j = 0; j < 2; j++) {
      const int row = wr * 32 + j * 16 + l16;
      f32x4 v = acc[i][j];
      unsigned short h0 = f2bf(fmaxf(v[0] + bv.x, 0.f));
      unsigned short h1 = f2bf(fmaxf(v[1] + bv.y, 0.f));
      unsigned short h2 = f2bf(fmaxf(v[2] + bv.z, 0.f));
      unsigned short h3 = f2bf(fmaxf(v[3] + bv.w, 0.f));
      uint2 p;
      p.x = (unsigned)h0 | ((unsigned)h1 << 16);
      p.y = (unsigned)h2 | ((unsigned)h3 << 16);
      unsigned off = (unsigned)(row * 512 + hcol * 2) ^ ((unsigned)(row & 7) << 4);
      *(uint2*)((char*)sH + off) = p;
    }
  }

  __syncthreads();   // sH visible; W2_0 already drained at kt=7 barrier

  // ---------------- GEMM2 (normal): acc2[iR][j] = g subtiles ----------------
  f32x4 acc2[2][8];
#pragma unroll
  for (int i = 0; i < 2; i++)
#pragma unroll
    for (int j = 0; j < 8; j++) acc2[i][j] = (f32x4){0.f, 0.f, 0.f, 0.f};

#pragma unroll
  for (int kt = 0; kt < 8; ++kt) {
    if (kt < 7) STAGE_W(gW2, kt + 1, (kt + 1) & 1);      // issue-early prefetch

    bf16x8 hf[2], wf2[8];
#pragma unroll
    for (int i = 0; i < 2; i++) {
      const int hrow = wr * 32 + i * 16 + l16;
      unsigned off = (unsigned)(hrow * 512 + kt * 64 + quad * 16) ^ ((unsigned)(hrow & 7) << 4);
      hf[i] = *(const bf16x8*)((const char*)sH + off);
    }
#pragma unroll
    for (int j = 0; j < 8; j++)
      wf2[j] = *(const bf16x8*)(&sW[kt & 1][(wn * 128 + j * 16 + l16) * 32 + quad * 8]);
#pragma unroll
    for (int i = 0; i < 2; i++)
#pragma unroll
      for (int j = 0; j < 8; j++)
        acc2[i][j] = __builtin_amdgcn_mfma_f32_16x16x32_bf16(hf[i], wf2[j], acc2[i][j], 0, 0, 0);
    __syncthreads();
  }

  // --------- final epilogue: +b2, rownorm (in-block), bf16 g writes ---------
  float b2v[8];
#pragma unroll
  for (int j = 0; j < 8; j++) b2v[j] = b2[wn * 128 + j * 16 + l16];
#pragma unroll
  for (int i = 0; i < 2; i++)
#pragma unroll
    for (int j = 0; j < 8; j++)
#pragma unroll
      for (int r = 0; r < 4; r++) acc2[i][j][r] += b2v[j];

  float ss[2][4];
#pragma unroll
  for (int i = 0; i < 2; i++)
#pragma unroll
    for (int r = 0; r < 4; r++) {
      float s = 0.f;
#pragma unroll
      for (int j = 0; j < 8; j++) s += acc2[i][j][r] * acc2[i][j][r];
      ss[i][r] = s;
    }
#pragma unroll
  for (int m = 1; m < 16; m <<= 1)
#pragma unroll
    for (int i = 0; i < 2; i++)
#pragma unroll
      for (int r = 0; r < 4; r++) ss[i][r] += __shfl_xor(ss[i][r], m, 64);
  if (l16 == 0) {
#pragma unroll
    for (int i = 0; i < 2; i++)
#pragma unroll
      for (int r = 0; r < 4; r++) ssb[wr * 32 + i * 16 + quad * 4 + r][wn] = ss[i][r];
  }
  __syncthreads();
  if (tid < 64) {
    float s2 = ssb[tid][0] + ssb[tid][1];
    rn[bm * 64 + tid] = 1.f / fmaxf(sqrtf(s2), EPS);
  }

#pragma unroll
  for (int i = 0; i < 2; i++)
#pragma unroll
    for (int j = 0; j < 8; j++) {
      const int gcol = wn * 128 + j * 16 + l16;
#pragma unroll
      for (int r = 0; r < 4; r++) {
        const size_t grow2 = bm * 64 + wr * 32 + i * 16 + quad * 4 + r;
        G[grow2 * H + gcol] = f2bf(acc2[i][j][r]);
      }
    }
#undef LOAD_A
#undef WRITE_A
#undef STAGE_W
}

__device__ __forceinline__ float dot_u4(uint4 a, uint4 b) {
  float s;
  s  = bflo(a.x) * bflo(b.x) + bfhi(a.x) * bfhi(b.x);
  s += bflo(a.y) * bflo(b.y) + bfhi(a.y) * bfhi(b.y);
  s += bflo(a.z) * bflo(b.z) + bfhi(a.z) * bfhi(b.z);
  s += bflo(a.w) * bflo(b.w) + bfhi(a.w) * bfhi(b.w);
  return s;
}

// 8 lanes per edge, 8 edges per wave, 32 edges per block.
__global__ __launch_bounds__(256) void edge_cos_kernel(
    const int* __restrict__ ei, const unsigned short* __restrict__ g,
    const float* __restrict__ rn, float* __restrict__ out, int E) {
  const int lane = threadIdx.x & 63;
  const int wid  = threadIdx.x >> 6;
  const int l8   = lane & 7;
  const int sub  = lane >> 3;
  const int e    = blockIdx.x * 32 + wid * 8 + sub;
  if (e >= E) return;
  const int c = ei[e], r = ei[E + e];
  const uint4* gc = (const uint4*)(g + (size_t)c * H);
  const uint4* gr = (const uint4*)(g + (size_t)r * H);
  uint4 a0 = gc[l8], a1 = gc[l8 + 8], a2 = gc[l8 + 16], a3 = gc[l8 + 24];
  uint4 b0 = gr[l8], b1 = gr[l8 + 8], b2 = gr[l8 + 16], b3 = gr[l8 + 24];
  float d = dot_u4(a0, b0) + dot_u4(a1, b1) + dot_u4(a2, b2) + dot_u4(a3, b3);
  d += __shfl_xor(d, 4, 8);
  d += __shfl_xor(d, 2, 8);
  d += __shfl_xor(d, 1, 8);
  if (l8 == 0) out[e] = d * rn[c] * rn[r];
}

extern "C" void kernel_launch(void* const* d_in, const int* in_sizes, int n_in,
                              void* d_out, int out_size, void* d_ws, size_t ws_size,
                              hipStream_t stream) {
  const float* emb = (const float*)d_in[0];
  const int*   ei  = (const int*)d_in[1];
  const float* W1  = (const float*)d_in[2];
  const float* b1  = (const float*)d_in[3];
  const float* W2  = (const float*)d_in[4];
  const float* b2  = (const float*)d_in[5];
  float* out = (float*)d_out;

  const int NH = in_sizes[0];              // N*H
  const int N  = NH / H;                   // 50000
  const int E  = in_sizes[1] / 2;          // 300000
  const int Mp = ((N + 63) / 64) * 64;     // 50048 (multiple of 64)

  char* ws = (char*)d_ws;
  unsigned short* gB   = (unsigned short*)ws; ws += (size_t)Mp * H * 2;
  unsigned short* w1B  = (unsigned short*)ws; ws += (size_t)H * H * 2;
  unsigned short* w2B  = (unsigned short*)ws; ws += (size_t)H * H * 2;
  float* rn            = (float*)ws;

  conv_w_kernel<<<(2 * H * H / 4 + 255) / 256, 256, 0, stream>>>(W1, W2, w1B, w2B);

  fused_mlp_kernel<<<Mp / 64, 256, 0, stream>>>(emb, w1B, w2B, b1, b2, gB, rn, N);

  edge_cos_kernel<<<(E + 31) / 32, 256, 0, stream>>>(ei, gB, rn, out, E);
}